// Round 20
// baseline (139.736 us; speedup 1.0000x reference)
//
#include <hip/hip_runtime.h>
#include <stdint.h>

// B=2 S=2048 D=1024 H=16 DH=64 ; SCALE=8 ; causal mask; IGNORE=-1e5
typedef __attribute__((ext_vector_type(8))) short bf16x8;
typedef __attribute__((ext_vector_type(4))) float f32x4;
typedef __attribute__((ext_vector_type(16))) float f32x16;
typedef __attribute__((ext_vector_type(4))) unsigned short us4;

#define LOG2E 1.44269504088896340736f

__device__ __forceinline__ unsigned short f2bf(float f) {
    union { float f; unsigned u; } v; v.f = f;
    unsigned r = v.u + 0x7FFFu + ((v.u >> 16) & 1u);
    return (unsigned short)(r >> 16);
}
__device__ __forceinline__ float bf2f(unsigned short u) {
    return __uint_as_float(((unsigned)u) << 16);
}

__device__ __forceinline__ unsigned cvtpk(float lo, float hi) {
    unsigned r;
    asm("v_cvt_pk_bf16_f32 %0, %1, %2" : "=v"(r) : "v"(lo), "v"(hi));
    return r;
}
// NOTE: plswap only safe when a and b hold DIFFERENT values (round-14 lesson).
__device__ __forceinline__ void plswap(unsigned &a, unsigned &b) {
    asm volatile("v_permlane32_swap_b32 %0, %1" : "+v"(a), "+v"(b));
}

__device__ __forceinline__ void gld16(const void* g, void* l) {
    __builtin_amdgcn_global_load_lds((const __attribute__((address_space(1))) void*)g,
                                     (__attribute__((address_space(3))) void*)l, 16, 0, 0);
}

// ---- fused conversions
__global__ void k_cvt_all(
    const float* __restrict__ x,  const float* __restrict__ WQ,
    const float* __restrict__ WK, const float* __restrict__ WV,
    const float* __restrict__ WO,
    unsigned short* __restrict__ xb,  unsigned short* __restrict__ wqb,
    unsigned short* __restrict__ wkb, unsigned short* __restrict__ wvb,
    unsigned short* __restrict__ wob)
{
    const int blk = blockIdx.x;
    if (blk < 7168) {
        const float* in; unsigned short* out; int base;
        if (blk < 4096)      { in = x;  out = xb;  base = blk; }
        else if (blk < 5120) { in = WQ; out = wqb; base = blk - 4096; }
        else if (blk < 6144) { in = WK; out = wkb; base = blk - 5120; }
        else                 { in = WV; out = wvb; base = blk - 6144; }
        int i = base * 256 + threadIdx.x;
        float4 v = ((const float4*)in)[i];
        us4 o; o.x = f2bf(v.x); o.y = f2bf(v.y); o.z = f2bf(v.z); o.w = f2bf(v.w);
        *(us4*)(out + (size_t)i * 4) = o;
    } else {
        int t = (blk - 7168) * 256 + threadIdx.x;   // 1M: wob[d][i*64+h]
        int d = t >> 10, nn = t & 1023, i = nn >> 6, h = nn & 63;
        wob[t] = f2bf(WO[(((size_t)i << 10) + d) * 64 + h]);
    }
}

// ---- QKV GEMM: asymmetric 128x64 tile, BK=128, 48KB LDS (round-17 form).
__global__ __launch_bounds__(256) void k_gemm_qkv(
    const unsigned short* __restrict__ Xb,
    const unsigned short* __restrict__ Wq, const unsigned short* __restrict__ Wk,
    const unsigned short* __restrict__ Wv,
    const float* __restrict__ bQ, const float* __restrict__ bK, const float* __restrict__ bV,
    unsigned short* __restrict__ Qb, unsigned short* __restrict__ Kb, unsigned short* __restrict__ VTb)
{
    __shared__ unsigned short As[128][128];   // 32 KB
    __shared__ unsigned short Bs[64][128];    // 16 KB
    const int which = blockIdx.z;
    const unsigned short* Wp = which == 0 ? Wq : (which == 1 ? Wk : Wv);
    const int bm = blockIdx.x, bn = blockIdx.y;
    const int t = threadIdx.x, lane = t & 63, w = t >> 6;
    const int l15 = lane & 15, l4 = lane >> 4;
    const int rsw = l15 & 7;
    const int c0 = w * 64 + lane;
    const int arow = bm << 7, brow = bn << 6;
    f32x4 acc[2][4] = {};

    for (int k0 = 0; k0 < 1024; k0 += 128) {
        #pragma unroll
        for (int it = 0; it < 8; ++it) {
            int c = it * 256 + c0;
            int row = c >> 4, sl = (c & 15) ^ (row & 7);
            gld16(Xb + ((size_t)(arow + row)) * 1024 + k0 + sl * 8, (char*)As + (c << 4));
        }
        #pragma unroll
        for (int it = 0; it < 4; ++it) {
            int c = it * 256 + c0;
            int row = c >> 4, sl = (c & 15) ^ (row & 7);
            gld16(Wp + ((size_t)(brow + row)) * 1024 + k0 + sl * 8, (char*)Bs + (c << 4));
        }
        __syncthreads();
        const char* Ab = (const char*)As;
        const char* Bb = (const char*)Bs;
        #pragma unroll
        for (int kk = 0; kk < 4; ++kk) {
            bf16x8 af[2], bfg[4];
            #pragma unroll
            for (int m = 0; m < 2; ++m)
                af[m] = *(const bf16x8*)(Ab + (w * 32 + m * 16 + l15) * 256 + (((kk * 4 + l4) ^ rsw) << 4));
            #pragma unroll
            for (int n = 0; n < 4; ++n)
                bfg[n] = *(const bf16x8*)(Bb + (n * 16 + l15) * 256 + (((kk * 4 + l4) ^ rsw) << 4));
            __builtin_amdgcn_s_setprio(1);
            #pragma unroll
            for (int m = 0; m < 2; ++m)
                #pragma unroll
                for (int n = 0; n < 4; ++n)
                    acc[m][n] = __builtin_amdgcn_mfma_f32_16x16x32_bf16(af[m], bfg[n], acc[m][n], 0, 0, 0);
            __builtin_amdgcn_s_setprio(0);
        }
        __syncthreads();
    }
    #pragma unroll
    for (int m = 0; m < 2; ++m) {
        #pragma unroll
        for (int n = 0; n < 4; ++n) {
            int col = (bn << 6) + n * 16 + l15;
            int i = col >> 6, h = col & 63;
            float bias = which == 0 ? bQ[col] : (which == 1 ? bK[col] : bV[col]);
            #pragma unroll
            for (int r = 0; r < 4; ++r) {
                int p = (bm << 7) + w * 32 + m * 16 + (l4 << 2) + r;
                int b = p >> 11, s = p & 2047;
                float v = acc[m][n][r] + bias;
                if (which == 0)
                    Qb[(((((size_t)b << 4) + i) << 11) + s) * 64 + h] = f2bf(v * (0.125f * LOG2E));
                else if (which == 1)
                    Kb[(((((size_t)b << 4) + i) << 11) + s) * 64 + h] = f2bf(v);
                else
                    VTb[(((((size_t)b << 4) + i) << 6) + h) * 2048 + s] = f2bf(v);
            }
        }
    }
}

// ---- flash attention, swapped-operand, 32x32x16 MFMA, LDS-staged K/V,
// split-KV (2 parts per q-chunk) with normalized-O + LSE partials.
// block = 128 thr (2 waves x 32 q rows); grid = 2048 1-D, LPT decode.
// PAIRED KV-tiles: 32KB LDS = two [K 8KB | V 8KB] halves; per pair of tiles:
//   barrier -> frags(A)+body(A) -> frags(B) -> barrier -> stage(next pair) -> body(B).
// Barrier count halves vs round-15; stage latency hides under body(B).
// State (m/l/za/qf) unchanged -> VGPR-neutral (unlike the q-axis fattening).
__global__ __launch_bounds__(128) void k_attn(
    const unsigned short* __restrict__ Qb, const unsigned short* __restrict__ Kb,
    const unsigned short* __restrict__ VTb,
    unsigned short* __restrict__ Zp, float* __restrict__ Lse)
{
    __shared__ __align__(16) char Lbuf[32768];   // [K0 8K|V0 8K|K1 8K|V1 8K]
    const int id = (int)blockIdx.x;
    const int bi = id & 31;
    const int r = id >> 5;
    const int c = 31 - (r >> 1);
    const int part = r & 1;
    const int n = c + 1, n0 = (n + 1) >> 1;
    const int t0 = part ? n0 : 0, t1 = part ? n : n0;
    const int lane = threadIdx.x & 63, w = threadIdx.x >> 6;
    const int l31 = lane & 31, hi = lane >> 5;
    const unsigned short* Qh = Qb + (size_t)bi * 2048 * 64;
    const char* Khb = (const char*)(Kb + (size_t)bi * 2048 * 64);   // [kv][64] rows 128B
    const char* Vhb = (const char*)(VTb + (size_t)bi * 64 * 2048);  // [dh][2048] rows 4096B
    const int q0 = c * 64 + w * 32;
    const int q = q0 + l31;

    bf16x8 qf[4];
    #pragma unroll
    for (int kk = 0; kk < 4; ++kk)
        qf[kk] = *(const bf16x8*)&Qh[(size_t)q * 64 + kk * 16 + hi * 8];

    const int r8 = lane >> 3;
    const int swz = ((lane & 7) * 16) ^ (r8 << 4);
    const int koff = r8 * 128 + swz;
    const int voff = r8 * 4096 + swz;

    const int rsw = (l31 & 7) << 4;
    int kaddr[8];
    #pragma unroll
    for (int i = 0; i < 8; ++i)
        kaddr[i] = (l31 + 32 * (i >> 2)) * 128 + ((32 * (i & 3) + 16 * hi) ^ rsw);
    int vcol[4];
    #pragma unroll
    for (int f = 0; f < 4; ++f)
        vcol[f] = ((f * 32 + 16 * hi) ^ rsw);

    f32x16 za0 = {}, za1 = {};
    float m_run = -1e30f, l_run = 0.f;

#define STAGE_T(TT, HALF)                                                         \
    if (w == 0) {                                                                 \
        const char* src_ = Khb + (size_t)(TT) * 8192 + koff;                      \
        _Pragma("unroll")                                                         \
        for (int it = 0; it < 8; ++it) gld16(src_ + it * 1024, &Lbuf[(HALF) * 16384] + it * 1024); \
    } else {                                                                      \
        const char* src_ = Vhb + (size_t)(TT) * 128 + voff;                       \
        _Pragma("unroll")                                                         \
        for (int it = 0; it < 8; ++it) gld16(src_ + it * 32768, &Lbuf[(HALF) * 16384 + 8192] + it * 1024); \
    }

#define READ_FRAGS(KL, VL, KA, V0, V1)                                            \
    {                                                                             \
        _Pragma("unroll")                                                         \
        for (int i = 0; i < 8; ++i) KA[i] = *(const bf16x8*)((KL) + kaddr[i]);    \
        _Pragma("unroll")                                                         \
        for (int f = 0; f < 4; ++f) {                                             \
            V0[f] = *(const bf16x8*)((VL) + l31 * 128 + vcol[f]);                 \
            V1[f] = *(const bf16x8*)((VL) + (l31 + 32) * 128 + vcol[f]);          \
        }                                                                         \
    }

#define BODY(T, KA, V0, V1)                                                       \
    {                                                                             \
        const bool full = !((T) == c && w == 0);                                  \
        f32x16 s0 = {}, s1;                                                       \
        __builtin_amdgcn_s_setprio(1);                                            \
        _Pragma("unroll")                                                         \
        for (int kk = 0; kk < 4; ++kk)                                            \
            s0 = __builtin_amdgcn_mfma_f32_32x32x16_bf16(KA[kk], qf[kk], s0, 0, 0, 0); \
        if (full) {                                                               \
            f32x16 z = {};                                                        \
            _Pragma("unroll")                                                     \
            for (int kk = 0; kk < 4; ++kk)                                        \
                z = __builtin_amdgcn_mfma_f32_32x32x16_bf16(KA[4 + kk], qf[kk], z, 0, 0, 0); \
            s1 = z;                                                               \
        }                                                                         \
        __builtin_amdgcn_s_setprio(0);                                            \
        if (!full) {                                                              \
            _Pragma("unroll")                                                     \
            for (int j = 0; j < 16; ++j) s1[j] = -100000.0f;                      \
        }                                                                         \
        if ((T) == c) {                                                           \
            _Pragma("unroll")                                                     \
            for (int j = 0; j < 16; ++j) {                                        \
                int kv0 = (j & 3) + 8 * (j >> 2) + 4 * hi;                        \
                if ((T) * 64 + kv0 > q) s0[j] = -100000.0f;                       \
                if ((T) * 64 + kv0 + 32 > q) s1[j] = -100000.0f;                  \
            }                                                                     \
        }                                                                         \
        float tmax = -1e30f;                                                      \
        _Pragma("unroll")                                                         \
        for (int j = 0; j < 16; ++j) tmax = fmaxf(tmax, fmaxf(s0[j], s1[j]));     \
        tmax = fmaxf(tmax, __shfl_xor(tmax, 32, 64));                             \
        if (!__all(tmax <= m_run + 8.0f)) {                                       \
            float newm = fmaxf(m_run, tmax);                                      \
            float alpha = exp2f(m_run - newm);                                    \
            m_run = newm;                                                         \
            l_run *= alpha;                                                       \
            za0 *= alpha; za1 *= alpha;                                           \
        }                                                                         \
        float rsum = 0.f;                                                         \
        _Pragma("unroll")                                                         \
        for (int j = 0; j < 16; ++j) { s0[j] = exp2f(s0[j] - m_run); rsum += s0[j]; } \
        if (full) {                                                               \
            _Pragma("unroll")                                                     \
            for (int j = 0; j < 16; ++j) { s1[j] = exp2f(s1[j] - m_run); rsum += s1[j]; } \
        }                                                                         \
        rsum += __shfl_xor(rsum, 32, 64);                                         \
        l_run += rsum;                                                            \
        union { unsigned u[4]; bf16x8 v; } pk0, pk1, pk2, pk3;                    \
        {                                                                         \
            unsigned a0 = cvtpk(s0[0], s0[1]),  a1 = cvtpk(s0[2], s0[3]);         \
            unsigned a2 = cvtpk(s0[4], s0[5]),  a3 = cvtpk(s0[6], s0[7]);         \
            plswap(a0, a2); plswap(a1, a3);                                       \
            pk0.u[0] = a0; pk0.u[1] = a1; pk0.u[2] = a2; pk0.u[3] = a3;           \
            unsigned b0 = cvtpk(s0[8], s0[9]),  b1 = cvtpk(s0[10], s0[11]);       \
            unsigned b2 = cvtpk(s0[12], s0[13]), b3 = cvtpk(s0[14], s0[15]);      \
            plswap(b0, b2); plswap(b1, b3);                                       \
            pk1.u[0] = b0; pk1.u[1] = b1; pk1.u[2] = b2; pk1.u[3] = b3;           \
        }                                                                         \
        if (full) {                                                               \
            unsigned a0 = cvtpk(s1[0], s1[1]),  a1 = cvtpk(s1[2], s1[3]);         \
            unsigned a2 = cvtpk(s1[4], s1[5]),  a3 = cvtpk(s1[6], s1[7]);         \
            plswap(a0, a2); plswap(a1, a3);                                       \
            pk2.u[0] = a0; pk2.u[1] = a1; pk2.u[2] = a2; pk2.u[3] = a3;           \
            unsigned b0 = cvtpk(s1[8], s1[9]),  b1 = cvtpk(s1[10], s1[11]);       \
            unsigned b2 = cvtpk(s1[12], s1[13]), b3 = cvtpk(s1[14], s1[15]);      \
            plswap(b0, b2); plswap(b1, b3);                                       \
            pk3.u[0] = b0; pk3.u[1] = b1; pk3.u[2] = b2; pk3.u[3] = b3;           \
        }                                                                         \
        __builtin_amdgcn_s_setprio(1);                                            \
        za0 = __builtin_amdgcn_mfma_f32_32x32x16_bf16(V0[0], pk0.v, za0, 0, 0, 0); \
        za1 = __builtin_amdgcn_mfma_f32_32x32x16_bf16(V1[0], pk0.v, za1, 0, 0, 0); \
        za0 = __builtin_amdgcn_mfma_f32_32x32x16_bf16(V0[1], pk1.v, za0, 0, 0, 0); \
        za1 = __builtin_amdgcn_mfma_f32_32x32x16_bf16(V1[1], pk1.v, za1, 0, 0, 0); \
        if (full) {                                                               \
            za0 = __builtin_amdgcn_mfma_f32_32x32x16_bf16(V0[2], pk2.v, za0, 0, 0, 0); \
            za1 = __builtin_amdgcn_mfma_f32_32x32x16_bf16(V1[2], pk2.v, za1, 0, 0, 0); \
            za0 = __builtin_amdgcn_mfma_f32_32x32x16_bf16(V0[3], pk3.v, za0, 0, 0, 0); \
            za1 = __builtin_amdgcn_mfma_f32_32x32x16_bf16(V1[3], pk3.v, za1, 0, 0, 0); \
        }                                                                         \
        __builtin_amdgcn_s_setprio(0);                                            \
    }

    // ---- prologue: stage first pair (guarded: empty parts issue no DMA)
    if (t0 < t1) {
        STAGE_T(t0, 0);
        if (t0 + 1 < t1) { STAGE_T(t0 + 1, 1); }
    }

    for (int tb = t0; tb < t1; tb += 2) {
        const bool hasB = (tb + 1 < t1);    // block-uniform
        __syncthreads();                    // stages landed (vmcnt drained)
        bf16x8 kaA[8], vA0[4], vA1[4];
        READ_FRAGS(&Lbuf[0], &Lbuf[8192], kaA, vA0, vA1);
        BODY(tb, kaA, vA0, vA1);
        bf16x8 kaB[8], vB0[4], vB1[4];
        if (hasB) READ_FRAGS(&Lbuf[16384], &Lbuf[24576], kaB, vB0, vB1);
        __syncthreads();                    // ALL reads of both halves done
        if (tb + 2 < t1) { STAGE_T(tb + 2, 0); }
        if (tb + 3 < t1) { STAGE_T(tb + 3, 1); }
        if (hasB) BODY(tb + 1, kaB, vB0, vB1);   // hides stage latency
    }
#undef STAGE_T
#undef READ_FRAGS
#undef BODY

    // ---- epilogue: normalized partial O + LSE
    const float rl = (l_run > 0.f) ? 1.0f / l_run : 0.f;
    const float lse = (l_run > 0.f) ? m_run + log2f(l_run) : -1e30f;
    const int pb = (part << 5) + bi;
    unsigned short* zp = Zp + ((size_t)pb * 2048 + q) * 64;
    #pragma unroll
    for (int nn = 0; nn < 2; ++nn) {
        #pragma unroll
        for (int gg = 0; gg < 4; ++gg) {
            int dh0 = nn * 32 + 8 * gg + 4 * hi;
            us4 o;
            float v0 = (nn ? za1[4 * gg + 0] : za0[4 * gg + 0]) * rl;
            float v1 = (nn ? za1[4 * gg + 1] : za0[4 * gg + 1]) * rl;
            float v2 = (nn ? za1[4 * gg + 2] : za0[4 * gg + 2]) * rl;
            float v3 = (nn ? za1[4 * gg + 3] : za0[4 * gg + 3]) * rl;
            o.x = f2bf(v0); o.y = f2bf(v1); o.z = f2bf(v2); o.w = f2bf(v3);
            *(us4*)(zp + dh0) = o;
        }
    }
    if (hi == 0) Lse[(size_t)pb * 2048 + q] = lse;
}

// ---- combine the 2 KV-part partials:  Zb[b][q][ih*64+dh]
__global__ __launch_bounds__(256) void k_combine(
    const unsigned short* __restrict__ Zp, const float* __restrict__ Lse,
    unsigned short* __restrict__ Zb)
{
    const int tid = blockIdx.x * 256 + threadIdx.x;   // 512K
    const int dc = tid & 7, q = (tid >> 3) & 2047, bi = tid >> 14;
    const float l0 = Lse[(size_t)bi * 2048 + q];
    const float l1 = Lse[(size_t)(32 + bi) * 2048 + q];
    const float M = fmaxf(l0, l1);
    float e0 = exp2f(l0 - M), e1 = exp2f(l1 - M);
    const float rs = 1.0f / (e0 + e1);
    e0 *= rs; e1 *= rs;
    const size_t base = ((size_t)bi * 2048 + q) * 64 + dc * 8;
    bf16x8 z0 = *(const bf16x8*)(Zp + base);
    bf16x8 z1 = *(const bf16x8*)(Zp + (size_t)32 * 2048 * 64 + base);
    const int b = bi >> 4, ih = bi & 15;
    unsigned short* op = Zb + (((size_t)b * 2048 + q) << 10) + ih * 64 + dc * 8;
    bf16x8 o;
    #pragma unroll
    for (int j = 0; j < 8; ++j) {
        float v = e0 * bf2f((unsigned short)z0[j]) + e1 * bf2f((unsigned short)z1[j]);
        o[j] = (short)f2bf(v);
    }
    *(bf16x8*)op = o;
}

// ---- output projection (asymmetric 128x64 tile, BK=128; round-17 form)
__global__ __launch_bounds__(256) void k_gemm_out(
    const unsigned short* __restrict__ Zb, const unsigned short* __restrict__ Wo,
    const float* __restrict__ bO, float* __restrict__ out)
{
    __shared__ unsigned short As[128][128];
    __shared__ unsigned short Bs[64][128];
    const int bm = blockIdx.x, bn = blockIdx.y;
    const int t = threadIdx.x, lane = t & 63, w = t >> 6;
    const int l15 = lane & 15, l4 = lane >> 4;
    const int rsw = l15 & 7;
    const int c0 = w * 64 + lane;
    const int arow = bm << 7, brow = bn << 6;
    f32x4 acc[2][4] = {};

    for (int k0 = 0; k0 < 1024; k0 += 128) {
        #pragma unroll
        for (int it = 0; it < 8; ++it) {
            int c = it * 256 + c0;
            int row = c >> 4, sl = (c & 15) ^ (row & 7);
            gld16(Zb + ((size_t)(arow + row)) * 1024 + k0 + sl * 8, (char*)As + (c << 4));
        }
        #pragma unroll
        for (int it = 0; it < 4; ++it) {
            int c = it * 256 + c0;
            int row = c >> 4, sl = (c & 15) ^ (row & 7);
            gld16(Wo + ((size_t)(brow + row)) * 1024 + k0 + sl * 8, (char*)Bs + (c << 4));
        }
        __syncthreads();
        const char* Ab = (const char*)As;
        const char* Bb = (const char*)Bs;
        #pragma unroll
        for (int kk = 0; kk < 4; ++kk) {
            bf16x8 af[2], bfg[4];
            #pragma unroll
            for (int m = 0; m < 2; ++m)
                af[m] = *(const bf16x8*)(Ab + (w * 32 + m * 16 + l15) * 256 + (((kk * 4 + l4) ^ rsw) << 4));
            #pragma unroll
            for (int n = 0; n < 4; ++n)
                bfg[n] = *(const bf16x8*)(Bb + (n * 16 + l15) * 256 + (((kk * 4 + l4) ^ rsw) << 4));
            __builtin_amdgcn_s_setprio(1);
            #pragma unroll
            for (int m = 0; m < 2; ++m)
                #pragma unroll
                for (int n = 0; n < 4; ++n)
                    acc[m][n] = __builtin_amdgcn_mfma_f32_16x16x32_bf16(af[m], bfg[n], acc[m][n], 0, 0, 0);
            __builtin_amdgcn_s_setprio(0);
        }
        __syncthreads();
    }
    #pragma unroll
    for (int m = 0; m < 2; ++m) {
        #pragma unroll
        for (int n = 0; n < 4; ++n) {
            int col = (bn << 6) + n * 16 + l15;
            float bias = bO[col];
            #pragma unroll
            for (int r = 0; r < 4; ++r) {
                int p = (bm << 7) + w * 32 + m * 16 + (l4 << 2) + r;
                out[(size_t)p * 1024 + col] = acc[m][n][r] + bias;
            }
        }
    }
}

extern "C" void kernel_launch(void* const* d_in, const int* in_sizes, int n_in,
                              void* d_out, int out_size, void* d_ws, size_t ws_size,
                              hipStream_t stream)
{
    const float* x  = (const float*)d_in[0];
    const float* WQ = (const float*)d_in[1];
    const float* WK = (const float*)d_in[2];
    const float* WV = (const float*)d_in[3];
    const float* WO = (const float*)d_in[4];
    const float* bQ = (const float*)d_in[5];
    const float* bK = (const float*)d_in[6];
    const float* bV = (const float*)d_in[7];
    const float* bO = (const float*)d_in[8];
    float* out = (float*)d_out;

    char* w = (char*)d_ws;
    unsigned short* xb  = (unsigned short*)w; w += (size_t)4096 * 1024 * 2;
    unsigned short* wqb = (unsigned short*)w; w += (size_t)1024 * 1024 * 2;
    unsigned short* wkb = (unsigned short*)w; w += (size_t)1024 * 1024 * 2;
    unsigned short* wvb = (unsigned short*)w; w += (size_t)1024 * 1024 * 2;
    unsigned short* wob = (unsigned short*)w; w += (size_t)1024 * 1024 * 2;
    unsigned short* Qb  = (unsigned short*)w; w += (size_t)4096 * 1024 * 2;
    unsigned short* Kb  = (unsigned short*)w; w += (size_t)4096 * 1024 * 2;
    unsigned short* VTb = (unsigned short*)w; w += (size_t)4096 * 1024 * 2;
    unsigned short* Zb  = (unsigned short*)w; w += (size_t)4096 * 1024 * 2;
    unsigned short* Zp  = (unsigned short*)w; w += (size_t)2 * 32 * 2048 * 64 * 2;
    float*          Lse = (float*)w;          w += (size_t)2 * 32 * 2048 * 4;

    k_cvt_all<<<11264, 256, 0, stream>>>(x, WQ, WK, WV, WO, xb, wqb, wkb, wvb, wob);

    k_gemm_qkv<<<dim3(32, 16, 3), 256, 0, stream>>>(xb, wqb, wkb, wvb, bQ, bK, bV, Qb, Kb, VTb);
    k_attn<<<2048, 128, 0, stream>>>(Qb, Kb, VTb, Zp, Lse);
    k_combine<<<2048, 256, 0, stream>>>(Zp, Lse, Zb);
    k_gemm_out<<<dim3(32, 16), 256, 0, stream>>>(Zb, wob, bO, out);
}

// Round 21
// 125.202 us; speedup vs baseline: 1.1161x; 1.1161x over previous
//
#include <hip/hip_runtime.h>
#include <stdint.h>

// B=2 S=2048 D=1024 H=16 DH=64 ; SCALE=8 ; causal mask; IGNORE=-1e5
typedef __attribute__((ext_vector_type(8))) short bf16x8;
typedef __attribute__((ext_vector_type(4))) float f32x4;
typedef __attribute__((ext_vector_type(16))) float f32x16;
typedef __attribute__((ext_vector_type(4))) unsigned short us4;

#define LOG2E 1.44269504088896340736f

__device__ __forceinline__ unsigned short f2bf(float f) {
    union { float f; unsigned u; } v; v.f = f;
    unsigned r = v.u + 0x7FFFu + ((v.u >> 16) & 1u);
    return (unsigned short)(r >> 16);
}
__device__ __forceinline__ float bf2f(unsigned short u) {
    return __uint_as_float(((unsigned)u) << 16);
}

__device__ __forceinline__ unsigned cvtpk(float lo, float hi) {
    unsigned r;
    asm("v_cvt_pk_bf16_f32 %0, %1, %2" : "=v"(r) : "v"(lo), "v"(hi));
    return r;
}
// NOTE: plswap only safe when a and b hold DIFFERENT values (round-14 lesson:
// same-value copies can be register-aliased -> in-register swap -> wrong).
__device__ __forceinline__ void plswap(unsigned &a, unsigned &b) {
    asm volatile("v_permlane32_swap_b32 %0, %1" : "+v"(a), "+v"(b));
}

__device__ __forceinline__ void gld16(const void* g, void* l) {
    __builtin_amdgcn_global_load_lds((const __attribute__((address_space(1))) void*)g,
                                     (__attribute__((address_space(3))) void*)l, 16, 0, 0);
}

// ---- fused conversions: blocks [0,4096) x ; [4096,5120) WQ ; [5120,6144) WK ;
// [6144,7168) WV ; [7168,11264) WO-transpose.
__global__ void k_cvt_all(
    const float* __restrict__ x,  const float* __restrict__ WQ,
    const float* __restrict__ WK, const float* __restrict__ WV,
    const float* __restrict__ WO,
    unsigned short* __restrict__ xb,  unsigned short* __restrict__ wqb,
    unsigned short* __restrict__ wkb, unsigned short* __restrict__ wvb,
    unsigned short* __restrict__ wob)
{
    const int blk = blockIdx.x;
    if (blk < 7168) {
        const float* in; unsigned short* out; int base;
        if (blk < 4096)      { in = x;  out = xb;  base = blk; }
        else if (blk < 5120) { in = WQ; out = wqb; base = blk - 4096; }
        else if (blk < 6144) { in = WK; out = wkb; base = blk - 5120; }
        else                 { in = WV; out = wvb; base = blk - 6144; }
        int i = base * 256 + threadIdx.x;
        float4 v = ((const float4*)in)[i];
        us4 o; o.x = f2bf(v.x); o.y = f2bf(v.y); o.z = f2bf(v.z); o.w = f2bf(v.w);
        *(us4*)(out + (size_t)i * 4) = o;
    } else {
        int t = (blk - 7168) * 256 + threadIdx.x;   // 1M: wob[d][i*64+h]
        int d = t >> 10, nn = t & 1023, i = nn >> 6, h = nn & 63;
        wob[t] = f2bf(WO[(((size_t)i << 10) + d) * 64 + h]);
    }
}

// ---- QKV GEMM: C[p,n] = sum_m X[p,m] * W[n,m]  (B^T form).
// ASYMMETRIC tile 128x64, BK=128: As 32KB + Bs 16KB = 48KB -> 3 blocks/CU.
// 4 waves; wave w owns rows [w*32, w*32+32) x all 64 cols: acc[2][4].
// Single-buffer stage->barrier->compute->barrier loop; T2 XOR swizzle
// (source sl=(c&15)^(row&7); read slot=(kk*4+l4)^(l15&7)).
__global__ __launch_bounds__(256) void k_gemm_qkv(
    const unsigned short* __restrict__ Xb,
    const unsigned short* __restrict__ Wq, const unsigned short* __restrict__ Wk,
    const unsigned short* __restrict__ Wv,
    const float* __restrict__ bQ, const float* __restrict__ bK, const float* __restrict__ bV,
    unsigned short* __restrict__ Qb, unsigned short* __restrict__ Kb, unsigned short* __restrict__ VTb)
{
    __shared__ unsigned short As[128][128];   // 32 KB
    __shared__ unsigned short Bs[64][128];    // 16 KB
    const int which = blockIdx.z;
    const unsigned short* Wp = which == 0 ? Wq : (which == 1 ? Wk : Wv);
    const int bm = blockIdx.x, bn = blockIdx.y;     // bm<32 (128 rows), bn<16 (64 cols)
    const int t = threadIdx.x, lane = t & 63, w = t >> 6;
    const int l15 = lane & 15, l4 = lane >> 4;
    const int rsw = l15 & 7;
    const int c0 = w * 64 + lane;   // 0..255
    const int arow = bm << 7, brow = bn << 6;
    f32x4 acc[2][4] = {};

    for (int k0 = 0; k0 < 1024; k0 += 128) {
        #pragma unroll
        for (int it = 0; it < 8; ++it) {           // A: 2048 16B-chunks
            int c = it * 256 + c0;
            int row = c >> 4, sl = (c & 15) ^ (row & 7);
            gld16(Xb + ((size_t)(arow + row)) * 1024 + k0 + sl * 8, (char*)As + (c << 4));
        }
        #pragma unroll
        for (int it = 0; it < 4; ++it) {           // B: 1024 16B-chunks
            int c = it * 256 + c0;
            int row = c >> 4, sl = (c & 15) ^ (row & 7);
            gld16(Wp + ((size_t)(brow + row)) * 1024 + k0 + sl * 8, (char*)Bs + (c << 4));
        }
        __syncthreads();
        const char* Ab = (const char*)As;
        const char* Bb = (const char*)Bs;
        #pragma unroll
        for (int kk = 0; kk < 4; ++kk) {
            bf16x8 af[2], bfg[4];
            #pragma unroll
            for (int m = 0; m < 2; ++m)
                af[m] = *(const bf16x8*)(Ab + (w * 32 + m * 16 + l15) * 256 + (((kk * 4 + l4) ^ rsw) << 4));
            #pragma unroll
            for (int n = 0; n < 4; ++n)
                bfg[n] = *(const bf16x8*)(Bb + (n * 16 + l15) * 256 + (((kk * 4 + l4) ^ rsw) << 4));
            __builtin_amdgcn_s_setprio(1);
            #pragma unroll
            for (int m = 0; m < 2; ++m)
                #pragma unroll
                for (int n = 0; n < 4; ++n)
                    acc[m][n] = __builtin_amdgcn_mfma_f32_16x16x32_bf16(af[m], bfg[n], acc[m][n], 0, 0, 0);
            __builtin_amdgcn_s_setprio(0);
        }
        __syncthreads();
    }
    #pragma unroll
    for (int m = 0; m < 2; ++m) {
        #pragma unroll
        for (int n = 0; n < 4; ++n) {
            int col = (bn << 6) + n * 16 + l15;   // n index = i*64+h
            int i = col >> 6, h = col & 63;
            float bias = which == 0 ? bQ[col] : (which == 1 ? bK[col] : bV[col]);
            #pragma unroll
            for (int r = 0; r < 4; ++r) {
                int p = (bm << 7) + w * 32 + m * 16 + (l4 << 2) + r;  // row = p
                int b = p >> 11, s = p & 2047;
                float v = acc[m][n][r] + bias;
                if (which == 0)
                    Qb[(((((size_t)b << 4) + i) << 11) + s) * 64 + h] = f2bf(v * (0.125f * LOG2E));
                else if (which == 1)
                    Kb[(((((size_t)b << 4) + i) << 11) + s) * 64 + h] = f2bf(v);
                else
                    VTb[(((((size_t)b << 4) + i) << 6) + h) * 2048 + s] = f2bf(v);
            }
        }
    }
}

// ---- flash attention, swapped-operand, 32x32x16 MFMA, LDS-staged K/V,
// split-KV (2 parts per q-chunk) with normalized-O + LSE partials.
// block = 128 thr (2 waves x 32 q rows); grid = 2048 1-D, LPT decode:
// bi = id&31, r = id>>5, c = 31-(r>>1), part = r&1 (heaviest parts first).
// Single 16KB LDS buffer (K 8KB | V 8KB), 2 barriers per tile.  (round-15 form)
__global__ __launch_bounds__(128) void k_attn(
    const unsigned short* __restrict__ Qb, const unsigned short* __restrict__ Kb,
    const unsigned short* __restrict__ VTb,
    unsigned short* __restrict__ Zp, float* __restrict__ Lse)
{
    __shared__ __align__(16) char Lbuf[16384];   // [ K 8KB | V 8KB ]
    const int id = (int)blockIdx.x;
    const int bi = id & 31;
    const int r = id >> 5;
    const int c = 31 - (r >> 1);
    const int part = r & 1;
    const int n = c + 1, n0 = (n + 1) >> 1;
    const int t0 = part ? n0 : 0, t1 = part ? n : n0;
    const int lane = threadIdx.x & 63, w = threadIdx.x >> 6;
    const int l31 = lane & 31, hi = lane >> 5;
    const unsigned short* Qh = Qb + (size_t)bi * 2048 * 64;
    const char* Khb = (const char*)(Kb + (size_t)bi * 2048 * 64);   // [kv][64 dh] rows 128B
    const char* Vhb = (const char*)(VTb + (size_t)bi * 64 * 2048);  // [dh][2048 kv] rows 4096B
    const int q0 = c * 64 + w * 32;
    const int q = q0 + l31;                        // this lane's q row

    // Q^T B-fragments: qf[kk] = Q[q][kk*16 + hi*8 .. +8)
    bf16x8 qf[4];
    #pragma unroll
    for (int kk = 0; kk < 4; ++kk)
        qf[kk] = *(const bf16x8*)&Qh[(size_t)q * 64 + kk * 16 + hi * 8];

    // ---- staging: per-lane swizzled source offset (LDS linear, source carries the XOR)
    const int r8 = lane >> 3;                       // row-within-8 group
    const int swz = ((lane & 7) * 16) ^ (r8 << 4);  // swizzled 16B slot within 128B row
    const int koff = r8 * 128 + swz;                // K: + it*1024 + t*8192
    const int voff = r8 * 4096 + swz;               // V: + it*32768 + t*128

    // ---- ds_read fragment byte-offsets (constant per lane)
    const int rsw = (l31 & 7) << 4;
    int kaddr[8];
    #pragma unroll
    for (int i = 0; i < 8; ++i)
        kaddr[i] = (l31 + 32 * (i >> 2)) * 128 + ((32 * (i & 3) + 16 * hi) ^ rsw);
    int vcol[4];
    #pragma unroll
    for (int f = 0; f < 4; ++f)
        vcol[f] = ((f * 32 + 16 * hi) ^ rsw);

    f32x16 za0 = {}, za1 = {};
    float m_run = -1e30f, l_run = 0.f;

    // ---- prologue: stage tile t0
    if (t0 < t1) {
        if (w == 0) {
            const char* src = Khb + (size_t)t0 * 8192 + koff;
            #pragma unroll
            for (int it = 0; it < 8; ++it) gld16(src + it * 1024, &Lbuf[0] + it * 1024);
        } else {
            const char* src = Vhb + (size_t)t0 * 128 + voff;
            #pragma unroll
            for (int it = 0; it < 8; ++it) gld16(src + it * 32768, &Lbuf[8192] + it * 1024);
        }
    }

    for (int t = t0; t < t1; ++t) {
        __syncthreads();   // stage for tile t landed (drains own vmcnt)
        const char* KL = &Lbuf[0];
        const char* VL = &Lbuf[8192];
        bf16x8 ka[8];
        #pragma unroll
        for (int i = 0; i < 8; ++i) ka[i] = *(const bf16x8*)(KL + kaddr[i]);
        bf16x8 vf0[4], vf1[4];
        #pragma unroll
        for (int f = 0; f < 4; ++f) {
            vf0[f] = *(const bf16x8*)(VL + l31 * 128 + vcol[f]);
            vf1[f] = *(const bf16x8*)(VL + (l31 + 32) * 128 + vcol[f]);
        }
        __syncthreads();   // all reads done; buffer free for next stage
        if (t + 1 < t1) {  // stage next tile (lands during compute below)
            if (w == 0) {
                const char* src = Khb + (size_t)(t + 1) * 8192 + koff;
                #pragma unroll
                for (int it = 0; it < 8; ++it) gld16(src + it * 1024, &Lbuf[0] + it * 1024);
            } else {
                const char* src = Vhb + (size_t)(t + 1) * 128 + voff;
                #pragma unroll
                for (int it = 0; it < 8; ++it) gld16(src + it * 32768, &Lbuf[8192] + it * 1024);
            }
        }

        const bool full = !(t == c && w == 0);     // wave0 diagonal: kv 32..63 all masked
        // ---- S^T = K * Q^T  (two 32-kv tiles)
        f32x16 s0 = {}, s1;
        __builtin_amdgcn_s_setprio(1);
        #pragma unroll
        for (int kk = 0; kk < 4; ++kk)
            s0 = __builtin_amdgcn_mfma_f32_32x32x16_bf16(ka[kk], qf[kk], s0, 0, 0, 0);
        if (full) {
            f32x16 z = {};
            #pragma unroll
            for (int kk = 0; kk < 4; ++kk)
                z = __builtin_amdgcn_mfma_f32_32x32x16_bf16(ka[4 + kk], qf[kk], z, 0, 0, 0);
            s1 = z;
        }
        __builtin_amdgcn_s_setprio(0);

        if (!full) {
            #pragma unroll
            for (int j = 0; j < 16; ++j) s1[j] = -100000.0f;
        }
        // ---- causal mask on diagonal tile
        if (t == c) {
            #pragma unroll
            for (int j = 0; j < 16; ++j) {
                int kv0 = (j & 3) + 8 * (j >> 2) + 4 * hi;          // within-tile kv of s0[j]
                if (c * 64 + kv0 > q) s0[j] = -100000.0f;
                if (c * 64 + kv0 + 32 > q) s1[j] = -100000.0f;
            }
        }
        // ---- online softmax, in-lane (lane owns q; lane^32 holds other half of kv)
        float tmax = -1e30f;
        #pragma unroll
        for (int j = 0; j < 16; ++j) tmax = fmaxf(tmax, fmaxf(s0[j], s1[j]));
        tmax = fmaxf(tmax, __shfl_xor(tmax, 32, 64));
        if (!__all(tmax <= m_run + 8.0f)) {        // defer-max (T13)
            float newm = fmaxf(m_run, tmax);
            float alpha = exp2f(m_run - newm);
            m_run = newm;
            l_run *= alpha;
            za0 *= alpha; za1 *= alpha;
        }
        float rsum = 0.f;
        #pragma unroll
        for (int j = 0; j < 16; ++j) { s0[j] = exp2f(s0[j] - m_run); rsum += s0[j]; }
        if (full) {
            #pragma unroll
            for (int j = 0; j < 16; ++j) { s1[j] = exp2f(s1[j] - m_run); rsum += s1[j]; }
        }
        rsum += __shfl_xor(rsum, 32, 64);
        l_run += rsum;

        // ---- P^T B-fragments via cvt_pk + permlane32_swap (T12)
        union { unsigned u[4]; bf16x8 v; } pk0, pk1, pk2, pk3;
        {
            unsigned a0 = cvtpk(s0[0], s0[1]),  a1 = cvtpk(s0[2], s0[3]);
            unsigned a2 = cvtpk(s0[4], s0[5]),  a3 = cvtpk(s0[6], s0[7]);
            plswap(a0, a2); plswap(a1, a3);
            pk0.u[0] = a0; pk0.u[1] = a1; pk0.u[2] = a2; pk0.u[3] = a3;
            unsigned b0 = cvtpk(s0[8], s0[9]),  b1 = cvtpk(s0[10], s0[11]);
            unsigned b2 = cvtpk(s0[12], s0[13]), b3 = cvtpk(s0[14], s0[15]);
            plswap(b0, b2); plswap(b1, b3);
            pk1.u[0] = b0; pk1.u[1] = b1; pk1.u[2] = b2; pk1.u[3] = b3;
        }
        if (full) {
            unsigned a0 = cvtpk(s1[0], s1[1]),  a1 = cvtpk(s1[2], s1[3]);
            unsigned a2 = cvtpk(s1[4], s1[5]),  a3 = cvtpk(s1[6], s1[7]);
            plswap(a0, a2); plswap(a1, a3);
            pk2.u[0] = a0; pk2.u[1] = a1; pk2.u[2] = a2; pk2.u[3] = a3;
            unsigned b0 = cvtpk(s1[8], s1[9]),  b1 = cvtpk(s1[10], s1[11]);
            unsigned b2 = cvtpk(s1[12], s1[13]), b3 = cvtpk(s1[14], s1[15]);
            plswap(b0, b2); plswap(b1, b3);
            pk3.u[0] = b0; pk3.u[1] = b1; pk3.u[2] = b2; pk3.u[3] = b3;
        }
        // ---- Z^T += V^T * P^T   (accumulator stays in lane<->q domain)
        __builtin_amdgcn_s_setprio(1);
        za0 = __builtin_amdgcn_mfma_f32_32x32x16_bf16(vf0[0], pk0.v, za0, 0, 0, 0);
        za1 = __builtin_amdgcn_mfma_f32_32x32x16_bf16(vf1[0], pk0.v, za1, 0, 0, 0);
        za0 = __builtin_amdgcn_mfma_f32_32x32x16_bf16(vf0[1], pk1.v, za0, 0, 0, 0);
        za1 = __builtin_amdgcn_mfma_f32_32x32x16_bf16(vf1[1], pk1.v, za1, 0, 0, 0);
        if (full) {
            za0 = __builtin_amdgcn_mfma_f32_32x32x16_bf16(vf0[2], pk2.v, za0, 0, 0, 0);
            za1 = __builtin_amdgcn_mfma_f32_32x32x16_bf16(vf1[2], pk2.v, za1, 0, 0, 0);
            za0 = __builtin_amdgcn_mfma_f32_32x32x16_bf16(vf0[3], pk3.v, za0, 0, 0, 0);
            za1 = __builtin_amdgcn_mfma_f32_32x32x16_bf16(vf1[3], pk3.v, za1, 0, 0, 0);
        }
        __builtin_amdgcn_s_setprio(0);
    }

    // ---- epilogue: normalized partial O + LSE
    const float rl = (l_run > 0.f) ? 1.0f / l_run : 0.f;
    const float lse = (l_run > 0.f) ? m_run + log2f(l_run) : -1e30f;
    const int pb = (part << 5) + bi;
    unsigned short* zp = Zp + ((size_t)pb * 2048 + q) * 64;
    #pragma unroll
    for (int nn = 0; nn < 2; ++nn) {
        #pragma unroll
        for (int gg = 0; gg < 4; ++gg) {
            int dh0 = nn * 32 + 8 * gg + 4 * hi;
            us4 o;
            float v0 = (nn ? za1[4 * gg + 0] : za0[4 * gg + 0]) * rl;
            float v1 = (nn ? za1[4 * gg + 1] : za0[4 * gg + 1]) * rl;
            float v2 = (nn ? za1[4 * gg + 2] : za0[4 * gg + 2]) * rl;
            float v3 = (nn ? za1[4 * gg + 3] : za0[4 * gg + 3]) * rl;
            o.x = f2bf(v0); o.y = f2bf(v1); o.z = f2bf(v2); o.w = f2bf(v3);
            *(us4*)(zp + dh0) = o;
        }
    }
    if (hi == 0) Lse[(size_t)pb * 2048 + q] = lse;
}

// ---- combine the 2 KV-part partials:  Zb[b][q][ih*64+dh]
__global__ __launch_bounds__(256) void k_combine(
    const unsigned short* __restrict__ Zp, const float* __restrict__ Lse,
    unsigned short* __restrict__ Zb)
{
    const int tid = blockIdx.x * 256 + threadIdx.x;   // 512K = 32 bi * 2048 q * 8 octets
    const int dc = tid & 7, q = (tid >> 3) & 2047, bi = tid >> 14;
    const float l0 = Lse[(size_t)bi * 2048 + q];
    const float l1 = Lse[(size_t)(32 + bi) * 2048 + q];
    const float M = fmaxf(l0, l1);
    float e0 = exp2f(l0 - M), e1 = exp2f(l1 - M);
    const float rs = 1.0f / (e0 + e1);
    e0 *= rs; e1 *= rs;
    const size_t base = ((size_t)bi * 2048 + q) * 64 + dc * 8;
    bf16x8 z0 = *(const bf16x8*)(Zp + base);
    bf16x8 z1 = *(const bf16x8*)(Zp + (size_t)32 * 2048 * 64 + base);
    const int b = bi >> 4, ih = bi & 15;
    unsigned short* op = Zb + (((size_t)b * 2048 + q) << 10) + ih * 64 + dc * 8;
    bf16x8 o;
    #pragma unroll
    for (int j = 0; j < 8; ++j) {
        float v = e0 * bf2f((unsigned short)z0[j]) + e1 * bf2f((unsigned short)z1[j]);
        o[j] = (short)f2bf(v);
    }
    *(bf16x8*)op = o;
}

// ---- output projection: out[p,d] = sum_n Z[p,n] * WOt[d,n] + bO[d]  (f32 out)
// Same asymmetric 128x64 tile, BK=128, 48KB LDS as k_gemm_qkv.
__global__ __launch_bounds__(256) void k_gemm_out(
    const unsigned short* __restrict__ Zb, const unsigned short* __restrict__ Wo,
    const float* __restrict__ bO, float* __restrict__ out)
{
    __shared__ unsigned short As[128][128];
    __shared__ unsigned short Bs[64][128];
    const int bm = blockIdx.x, bn = blockIdx.y;     // bm<32, bn<16
    const int t = threadIdx.x, lane = t & 63, w = t >> 6;
    const int l15 = lane & 15, l4 = lane >> 4;
    const int rsw = l15 & 7;
    const int c0 = w * 64 + lane;
    const int arow = bm << 7, brow = bn << 6;
    f32x4 acc[2][4] = {};

    for (int k0 = 0; k0 < 1024; k0 += 128) {
        #pragma unroll
        for (int it = 0; it < 8; ++it) {
            int c = it * 256 + c0;
            int row = c >> 4, sl = (c & 15) ^ (row & 7);
            gld16(Zb + ((size_t)(arow + row)) * 1024 + k0 + sl * 8, (char*)As + (c << 4));
        }
        #pragma unroll
        for (int it = 0; it < 4; ++it) {
            int c = it * 256 + c0;
            int row = c >> 4, sl = (c & 15) ^ (row & 7);
            gld16(Wo + ((size_t)(brow + row)) * 1024 + k0 + sl * 8, (char*)Bs + (c << 4));
        }
        __syncthreads();
        const char* Ab = (const char*)As;
        const char* Bb = (const char*)Bs;
        #pragma unroll
        for (int kk = 0; kk < 4; ++kk) {
            bf16x8 af[2], bfg[4];
            #pragma unroll
            for (int m = 0; m < 2; ++m)
                af[m] = *(const bf16x8*)(Ab + (w * 32 + m * 16 + l15) * 256 + (((kk * 4 + l4) ^ rsw) << 4));
            #pragma unroll
            for (int n = 0; n < 4; ++n)
                bfg[n] = *(const bf16x8*)(Bb + (n * 16 + l15) * 256 + (((kk * 4 + l4) ^ rsw) << 4));
            __builtin_amdgcn_s_setprio(1);
            #pragma unroll
            for (int m = 0; m < 2; ++m)
                #pragma unroll
                for (int n = 0; n < 4; ++n)
                    acc[m][n] = __builtin_amdgcn_mfma_f32_16x16x32_bf16(af[m], bfg[n], acc[m][n], 0, 0, 0);
            __builtin_amdgcn_s_setprio(0);
        }
        __syncthreads();
    }
    #pragma unroll
    for (int m = 0; m < 2; ++m) {
        #pragma unroll
        for (int n = 0; n < 4; ++n) {
            int col = (bn << 6) + n * 16 + l15;
            float bias = bO[col];
            #pragma unroll
            for (int r = 0; r < 4; ++r) {
                int p = (bm << 7) + w * 32 + m * 16 + (l4 << 2) + r;
                out[(size_t)p * 1024 + col] = acc[m][n][r] + bias;
            }
        }
    }
}

extern "C" void kernel_launch(void* const* d_in, const int* in_sizes, int n_in,
                              void* d_out, int out_size, void* d_ws, size_t ws_size,
                              hipStream_t stream)
{
    const float* x  = (const float*)d_in[0];
    const float* WQ = (const float*)d_in[1];
    const float* WK = (const float*)d_in[2];
    const float* WV = (const float*)d_in[3];
    const float* WO = (const float*)d_in[4];
    const float* bQ = (const float*)d_in[5];
    const float* bK = (const float*)d_in[6];
    const float* bV = (const float*)d_in[7];
    const float* bO = (const float*)d_in[8];
    float* out = (float*)d_out;

    char* w = (char*)d_ws;
    unsigned short* xb  = (unsigned short*)w; w += (size_t)4096 * 1024 * 2;  // x bf16 [4096][1024]
    unsigned short* wqb = (unsigned short*)w; w += (size_t)1024 * 1024 * 2;
    unsigned short* wkb = (unsigned short*)w; w += (size_t)1024 * 1024 * 2;
    unsigned short* wvb = (unsigned short*)w; w += (size_t)1024 * 1024 * 2;
    unsigned short* wob = (unsigned short*)w; w += (size_t)1024 * 1024 * 2;  // [d][i*64+h]
    unsigned short* Qb  = (unsigned short*)w; w += (size_t)4096 * 1024 * 2;  // [B][H][S][DH] (pre-scaled)
    unsigned short* Kb  = (unsigned short*)w; w += (size_t)4096 * 1024 * 2;  // [B][H][S][DH]
    unsigned short* VTb = (unsigned short*)w; w += (size_t)4096 * 1024 * 2;  // [B][H][DH][S]
    unsigned short* Zb  = (unsigned short*)w; w += (size_t)4096 * 1024 * 2;  // [B][S][H*DH]
    unsigned short* Zp  = (unsigned short*)w; w += (size_t)2 * 32 * 2048 * 64 * 2;  // partial O (normalized)
    float*          Lse = (float*)w;          w += (size_t)2 * 32 * 2048 * 4;       // partial LSE

    k_cvt_all<<<11264, 256, 0, stream>>>(x, WQ, WK, WV, WO, xb, wqb, wkb, wvb, wob);

    k_gemm_qkv<<<dim3(32, 16, 3), 256, 0, stream>>>(xb, wqb, wkb, wvb, bQ, bK, bV, Qb, Kb, VTb);
    k_attn<<<2048, 128, 0, stream>>>(Qb, Kb, VTb, Zp, Lse);
    k_combine<<<2048, 256, 0, stream>>>(Zp, Lse, Zb);
    k_gemm_out<<<dim3(32, 16), 256, 0, stream>>>(Zb, wob, bO, out);
}